// Round 16
// baseline (104517.554 us; speedup 1.0000x reference)
//
#include <hip/hip_runtime.h>

#define BB   64
#define TT   1024
#define II   256
#define HH   512
#define NBLK 4          // batch groups of 16 rows — zero inter-block communication
#define NTHR 512
#define CLIPV 5.0f

#define NKT  24         // K-tiles of 32: kt 0..15 = h (512), 16..23 = x (256)
#define WB_ELEMS (96*24*64*8)    // 1,179,648 : [ct][kt][lane][j]
#define XA_DWORDS (BB*TT*II)     // 16,777,216 (64 MB)

typedef __attribute__((ext_vector_type(8))) short short8;
typedef __attribute__((ext_vector_type(4))) float f32x4;

// ---------- bf16 helpers (RNE) ----------
__device__ __forceinline__ unsigned short f2bf(float f){
    unsigned u = __float_as_uint(f);
    u += 0x7fffu + ((u >> 16) & 1u);
    return (unsigned short)(u >> 16);
}
__device__ __forceinline__ float bf2f(unsigned short s){
    return __uint_as_float(((unsigned)s) << 16);
}
// fp32 -> (hi,lo) bf16 pair packed in one dword (hi in low 16)
__device__ __forceinline__ unsigned packsplit(float f){
    unsigned short hi = f2bf(f);
    unsigned short lo = f2bf(f - bf2f(hi));
    return (unsigned)hi | ((unsigned)lo << 16);
}
__device__ __forceinline__ void unpack8(const uint4 a, const uint4 b, short8 &hi, short8 &lo){
    hi[0]=(short)a.x; lo[0]=(short)(a.x>>16);
    hi[1]=(short)a.y; lo[1]=(short)(a.y>>16);
    hi[2]=(short)a.z; lo[2]=(short)(a.z>>16);
    hi[3]=(short)a.w; lo[3]=(short)(a.w>>16);
    hi[4]=(short)b.x; lo[4]=(short)(b.x>>16);
    hi[5]=(short)b.y; lo[5]=(short)(b.y>>16);
    hi[6]=(short)b.z; lo[6]=(short)(b.z>>16);
    hi[7]=(short)b.w; lo[7]=(short)(b.w>>16);
}
#define SPLIT1(f, j) { float f_=(f); unsigned short h_=f2bf(f_); hi[j]=(short)h_; lo[j]=(short)f2bf(f_-bf2f(h_)); }
__device__ __forceinline__ void split8(const float4 a, const float4 b, short8 &hi, short8 &lo){
    SPLIT1(a.x,0) SPLIT1(a.y,1) SPLIT1(a.z,2) SPLIT1(a.w,3)
    SPLIT1(b.x,4) SPLIT1(b.y,5) SPLIT1(b.z,6) SPLIT1(b.w,7)
}
#undef SPLIT1
__device__ __forceinline__ f32x4 mfma(short8 a, short8 b, f32x4 c){
    return __builtin_amdgcn_mfma_f32_16x16x32_bf16(a, b, c, 0, 0, 0);
}

// ---- pre-pack W into B-fragment order (hi/lo separated: zero unpack in hot loop) ----
// wb[ct][kt][lane][j] = W[gcol = ct*16 + (lane&15)][k = kt*32 + (lane>>4)*8 + j]
// gate cols: z 0..511 | r 512..1023 | n 1024..1535 ; k<512 -> Whh, else Wih.
extern "C" __global__ void pack_w_kernel(const float* __restrict__ Wih,
                                         const float* __restrict__ Whh,
                                         unsigned short* __restrict__ wbh,
                                         unsigned short* __restrict__ wbl){
    int idx = blockIdx.x*256 + threadIdx.x;
    if (idx >= WB_ELEMS) return;
    int j = idx & 7, lane = (idx >> 3) & 63;
    int tmp = idx >> 9;               // ct*24 + kt
    int kt = tmp % 24, ct = tmp / 24;
    int q = lane >> 4, li = lane & 15;
    int gcol = ct*16 + li;
    int k = kt*32 + q*8 + j;
    float v = (k < HH) ? Whh[(size_t)gcol*HH + k] : Wih[(size_t)gcol*II + (k - HH)];
    unsigned short hv = f2bf(v);
    wbh[idx] = hv;
    wbl[idx] = f2bf(v - bf2f(hv));
}

// ---- pre-pack x into A-fragment order pair-dwords (coalesced per-step loads) ----
// xa[((bg*TT + t)*8 + kx)*64 + lane][j] = pair(x[row = bg*16 + (lane&15)][t][k = kx*32 + (lane>>4)*8 + j])
extern "C" __global__ void pack_xa_kernel(const float* __restrict__ x,
                                          unsigned* __restrict__ xa){
    int idx = blockIdx.x*256 + threadIdx.x;
    if (idx >= XA_DWORDS) return;
    int j = idx & 7, lane = (idx >> 3) & 63;
    int kx = (idx >> 9) & 7, t = (idx >> 12) & 1023, bg = idx >> 22;
    int q = lane >> 4, li = lane & 15;
    int row = bg*16 + li, k = kx*32 + q*8 + j;
    xa[idx] = packsplit(x[((size_t)row*TT + t)*II + k]);
}

// LDS: hfr [16kt][2 j4][64 lanes] uint4 (32KB) + rfr same (32KB) = 64KB
#define LDS_BYTES 65536

extern "C" __global__ void __launch_bounds__(NTHR, 2) gru_scan(
    const float* __restrict__ x,  const float* __restrict__ h0,
    const float* __restrict__ bih, const float* __restrict__ bhh,
    float* __restrict__ out,
    const unsigned short* __restrict__ wbh,
    const unsigned short* __restrict__ wbl,
    const unsigned* __restrict__ xa)
{
    extern __shared__ char smem[];
    uint4* hfr = (uint4*)smem;      // h  as bf16 pairs, A-frag order
    uint4* rfr = hfr + 2048;        // r*h as bf16 pairs, A-frag order

    const int tid = threadIdx.x, bg = blockIdx.x;
    const int w = tid >> 6, lane = tid & 63, quad = lane >> 4, li = lane & 15;

    // ---- init h fragments in LDS ----
    for (int it = 0; it < 16; ++it){
        int d = it*NTHR + tid;              // dword index 0..8191
        int dw = d & 3, u4i = d >> 2;
        int lane2 = u4i & 63, plane = u4i >> 6;
        int kt = plane >> 1, j4 = plane & 1;
        int col = kt*32 + (lane2 >> 4)*8 + j4*4 + dw;
        int row = lane2 & 15;
        ((unsigned*)hfr)[d] = packsplit(h0[(size_t)(bg*16 + row)*HH + col]);
    }

    // ---- per-wave constants: biases + own h in registers ----
    float h_own[4][4], bz[4], br[4], bn_[4];
    #pragma unroll
    for (int c = 0; c < 4; ++c){
        int col = w*64 + c*16 + li;
        bz[c]  = bih[col]        + bhh[col];
        br[c]  = bih[HH + col]   + bhh[HH + col];
        bn_[c] = bih[2*HH + col] + bhh[2*HH + col];
        #pragma unroll
        for (int i = 0; i < 4; ++i)
            h_own[c][i] = h0[(size_t)(bg*16 + quad*4 + i)*HH + col];
    }
    __syncthreads();

    const int ctz0 = w*4, ctr0 = 32 + w*4, ctn0 = 64 + w*4;
    float zh[4][4], omz[4][4];

    for (int t = 0; t < TT; ++t){
        // ================= phase 1 : z, r pre-activations =================
        f32x4 az[4], ar[4];
        #pragma unroll
        for (int c = 0; c < 4; ++c){ az[c] = (f32x4){0,0,0,0}; ar[c] = (f32x4){0,0,0,0}; }

        #pragma unroll 2
        for (int kt = 0; kt < 16; ++kt){              // h-part
            uint4 p0 = hfr[(kt*2+0)*64 + lane];
            uint4 p1 = hfr[(kt*2+1)*64 + lane];
            short8 ahi, alo; unpack8(p0, p1, ahi, alo);
            #pragma unroll
            for (int c = 0; c < 4; ++c){
                int bi = (((ctz0+c)*NKT + kt)*64 + lane)*8;
                short8 bh = *(const short8*)(wbh + bi);
                short8 bl = *(const short8*)(wbl + bi);
                az[c] = mfma(ahi,bh,az[c]); az[c] = mfma(ahi,bl,az[c]); az[c] = mfma(alo,bh,az[c]);
            }
            #pragma unroll
            for (int c = 0; c < 4; ++c){
                int bi = (((ctr0+c)*NKT + kt)*64 + lane)*8;
                short8 bh = *(const short8*)(wbh + bi);
                short8 bl = *(const short8*)(wbl + bi);
                ar[c] = mfma(ahi,bh,ar[c]); ar[c] = mfma(ahi,bl,ar[c]); ar[c] = mfma(alo,bh,ar[c]);
            }
        }
        #pragma unroll 2
        for (int kx = 0; kx < 8; ++kx){               // x-part
            short8 ahi, alo;
            if (xa){
                const uint4* xp4 = (const uint4*)xa + ((((size_t)bg*TT + t)*8 + kx)*64 + lane)*2;
                unpack8(xp4[0], xp4[1], ahi, alo);
            } else {
                const float* xb = x + ((size_t)(bg*16 + li)*TT + t)*II + kx*32 + quad*8;
                split8(*(const float4*)xb, *(const float4*)(xb+4), ahi, alo);
            }
            int kt = 16 + kx;
            #pragma unroll
            for (int c = 0; c < 4; ++c){
                int bi = (((ctz0+c)*NKT + kt)*64 + lane)*8;
                short8 bh = *(const short8*)(wbh + bi);
                short8 bl = *(const short8*)(wbl + bi);
                az[c] = mfma(ahi,bh,az[c]); az[c] = mfma(ahi,bl,az[c]); az[c] = mfma(alo,bh,az[c]);
            }
            #pragma unroll
            for (int c = 0; c < 4; ++c){
                int bi = (((ctr0+c)*NKT + kt)*64 + lane)*8;
                short8 bh = *(const short8*)(wbh + bi);
                short8 bl = *(const short8*)(wbl + bi);
                ar[c] = mfma(ahi,bh,ar[c]); ar[c] = mfma(ahi,bl,ar[c]); ar[c] = mfma(alo,bh,ar[c]);
            }
        }

        // gates: z kept in regs; r*h scattered to rfr (A-frag order)
        #pragma unroll
        for (int c = 0; c < 4; ++c){
            int col = w*64 + c*16 + li;
            int kt2 = col >> 5, j4 = (col >> 2) & 1, dwi = col & 3;
            int lbase = ((kt2*2 + j4)*64 + ((col >> 3) & 3)*16 + quad*4);
            #pragma unroll
            for (int i = 0; i < 4; ++i){
                float zv = 1.f/(1.f + __expf(-(az[c][i] + bz[c])));
                zh[c][i] = zv*h_own[c][i]; omz[c][i] = 1.f - zv;
                float rv = 1.f/(1.f + __expf(-(ar[c][i] + br[c])));
                ((unsigned*)rfr)[(lbase + i)*4 + dwi] = packsplit(rv*h_own[c][i]);
            }
        }
        __syncthreads();

        // ================= phase 2 : n, blend, write h =================
        f32x4 an[4];
        #pragma unroll
        for (int c = 0; c < 4; ++c) an[c] = (f32x4){0,0,0,0};

        #pragma unroll 2
        for (int kt = 0; kt < 16; ++kt){              // (r*h)-part
            uint4 p0 = rfr[(kt*2+0)*64 + lane];
            uint4 p1 = rfr[(kt*2+1)*64 + lane];
            short8 ahi, alo; unpack8(p0, p1, ahi, alo);
            #pragma unroll
            for (int c = 0; c < 4; ++c){
                int bi = (((ctn0+c)*NKT + kt)*64 + lane)*8;
                short8 bh = *(const short8*)(wbh + bi);
                short8 bl = *(const short8*)(wbl + bi);
                an[c] = mfma(ahi,bh,an[c]); an[c] = mfma(ahi,bl,an[c]); an[c] = mfma(alo,bh,an[c]);
            }
        }
        #pragma unroll 2
        for (int kx = 0; kx < 8; ++kx){               // x-part (same A-frags as phase 1)
            short8 ahi, alo;
            if (xa){
                const uint4* xp4 = (const uint4*)xa + ((((size_t)bg*TT + t)*8 + kx)*64 + lane)*2;
                unpack8(xp4[0], xp4[1], ahi, alo);
            } else {
                const float* xb = x + ((size_t)(bg*16 + li)*TT + t)*II + kx*32 + quad*8;
                split8(*(const float4*)xb, *(const float4*)(xb+4), ahi, alo);
            }
            int kt = 16 + kx;
            #pragma unroll
            for (int c = 0; c < 4; ++c){
                int bi = (((ctn0+c)*NKT + kt)*64 + lane)*8;
                short8 bh = *(const short8*)(wbh + bi);
                short8 bl = *(const short8*)(wbl + bi);
                an[c] = mfma(ahi,bh,an[c]); an[c] = mfma(ahi,bl,an[c]); an[c] = mfma(alo,bh,an[c]);
            }
        }

        // blend + publish h (LDS only — no global h, no flags, no atomics)
        #pragma unroll
        for (int c = 0; c < 4; ++c){
            int col = w*64 + c*16 + li;
            int kt2 = col >> 5, j4 = (col >> 2) & 1, dwi = col & 3;
            int lbase = ((kt2*2 + j4)*64 + ((col >> 3) & 3)*16 + quad*4);
            #pragma unroll
            for (int i = 0; i < 4; ++i){
                float nv = tanhf(an[c][i] + bn_[c]);
                float hv = zh[c][i] + omz[c][i]*nv;
                hv = fminf(fmaxf(hv, -CLIPV), CLIPV);
                h_own[c][i] = hv;
                ((unsigned*)hfr)[(lbase + i)*4 + dwi] = packsplit(hv);
                out[((size_t)(bg*16 + quad*4 + i)*TT + t)*HH + col] = hv;
                if (t == TT-1) out[(size_t)BB*TT*HH + (size_t)(bg*16 + quad*4 + i)*HH + col] = hv;
            }
        }
        __syncthreads();
    }
}

extern "C" void kernel_launch(void* const* d_in, const int* in_sizes, int n_in,
                              void* d_out, int out_size, void* d_ws, size_t ws_size,
                              hipStream_t stream) {
    const float* x   = (const float*)d_in[0];
    const float* h0  = (const float*)d_in[1];
    const float* Wih = (const float*)d_in[2];
    const float* bih = (const float*)d_in[3];
    const float* Whh = (const float*)d_in[4];
    const float* bhh = (const float*)d_in[5];
    float* out = (float*)d_out;

    // ws layout: [wbh 2.25MB][wbl 2.25MB][optional xa 64MB]
    const size_t WB_BYTES = (size_t)WB_ELEMS * 2;
    unsigned short* wbh = (unsigned short*)d_ws;
    unsigned short* wbl = wbh + WB_ELEMS;
    unsigned* xa = nullptr;
    if (ws_size >= 2*WB_BYTES + (size_t)XA_DWORDS*4)
        xa = (unsigned*)((char*)d_ws + 2*WB_BYTES);

    pack_w_kernel<<<dim3((WB_ELEMS + 255)/256), dim3(256), 0, stream>>>(Wih, Whh, wbh, wbl);
    if (xa)
        pack_xa_kernel<<<dim3((XA_DWORDS + 255)/256), dim3(256), 0, stream>>>(x, xa);

    (void)hipFuncSetAttribute((const void*)gru_scan,
                              hipFuncAttributeMaxDynamicSharedMemorySize, LDS_BYTES);
    gru_scan<<<dim3(NBLK), dim3(NTHR), LDS_BYTES, stream>>>(
        x, h0, bih, bhh, out, wbh, wbl, xa);
}